// Round 3
// baseline (228.506 us; speedup 1.0000x reference)
//
#include <hip/hip_runtime.h>
#include <hip/hip_bf16.h>

typedef short short8 __attribute__((ext_vector_type(8)));
typedef short short4_ __attribute__((ext_vector_type(4)));
typedef float float4_ __attribute__((ext_vector_type(4)));
typedef unsigned short ushort_t;
typedef unsigned int uint32_t_;
typedef uint32_t_ uint2v __attribute__((ext_vector_type(2)));
typedef uint32_t_ uint4v __attribute__((ext_vector_type(4)));

#define SCL 0.1803368801111f   // log2(e)/sqrt(64), folded into Q via gemm1 epilogue

__device__ __forceinline__ ushort_t f2bf(float f) {
    uint32_t_ u = __builtin_bit_cast(uint32_t_, f);
    u = (u + 0x7fffu + ((u >> 16) & 1u)) >> 16;
    return (ushort_t)u;
}

// pack two floats to bf16x2 (round-half-up on mantissa), a in low half
__device__ __forceinline__ uint32_t_ pack_bf16(float a, float b) {
    uint32_t_ ua = __builtin_bit_cast(uint32_t_, a) + 0x8000u;
    uint32_t_ ub = __builtin_bit_cast(uint32_t_, b) + 0x8000u;
    return __builtin_amdgcn_perm(ub, ua, 0x07060302);
}

__device__ __forceinline__ float4_ mfma16x16x16_bf16(short4_ a, short4_ b, float4_ c) {
#if __has_builtin(__builtin_amdgcn_mfma_f32_16x16x16bf16_1k)
    return __builtin_amdgcn_mfma_f32_16x16x16bf16_1k(a, b, c, 0, 0, 0);
#else
    asm volatile("v_mfma_f32_16x16x16_bf16 %0, %1, %2, %0" : "+v"(c) : "v"(a), "v"(b));
    return c;
#endif
}

#define MFMA32(a, b, c) __builtin_amdgcn_mfma_f32_16x16x32_bf16(a, b, c, 0, 0, 0)

#define GLD_LDS16(g, l) __builtin_amdgcn_global_load_lds( \
    (const __attribute__((address_space(1))) void*)(g),   \
    (__attribute__((address_space(3))) void*)(l), 16, 0, 0)

// ---------------- convert fp32 -> bf16 ----------------
__global__ void cvt_bf16_k(const float* __restrict__ in, ushort_t* __restrict__ out, int n) {
    int i = (blockIdx.x * blockDim.x + threadIdx.x) * 4;
    if (i + 3 < n) {
        float4 v = *(const float4*)(in + i);
        uint32_t_ lo = (uint32_t_)f2bf(v.x) | ((uint32_t_)f2bf(v.y) << 16);
        uint32_t_ hi = (uint32_t_)f2bf(v.z) | ((uint32_t_)f2bf(v.w) << 16);
        *(uint2*)(out + i) = make_uint2(lo, hi);
    }
}

// ---------------- transpose [K][N] fp32 -> [N][K] bf16 ----------------
__global__ void transpose_bf16_k(const float* __restrict__ in, ushort_t* __restrict__ out,
                                 int K, int N) {
    __shared__ float tile[32][33];
    int n0 = blockIdx.x * 32, k0 = blockIdx.y * 32;
    int tx = threadIdx.x & 31, ty = threadIdx.x >> 5;
    #pragma unroll
    for (int i = 0; i < 32; i += 8)
        tile[ty + i][tx] = in[(size_t)(k0 + ty + i) * N + n0 + tx];
    __syncthreads();
    #pragma unroll
    for (int i = 0; i < 32; i += 8)
        out[(size_t)(n0 + ty + i) * K + k0 + tx] = f2bf(tile[tx][ty + i]);
}

// ---------------- GEMM (m97-style): C[M][N] = A[M][K] @ Bt[N][K]^T + bias ----------------
template <bool OUT_BF16, bool SCALE_Q>
__global__ __launch_bounds__(256, 2)
void gemm_bt_k(const ushort_t* __restrict__ A, const ushort_t* __restrict__ Bt,
               const float* __restrict__ bias, void* __restrict__ C,
               int M, int N, int K) {
    __shared__ ushort_t As[128 * 32];
    __shared__ ushort_t Bs[128 * 32];
    const int tid  = threadIdx.x;
    const int m0   = blockIdx.y * 128;
    const int n0   = blockIdx.x * 128;
    const int w    = tid >> 6;
    const int lane = tid & 63;
    const int wm   = (w >> 1) * 64;
    const int wn   = (w & 1) * 64;
    const int quad = lane >> 4;
    const int l16  = lane & 15;

    const int srow0 = 16 * w + (lane >> 2);
    const int srow1 = 16 * (w + 4) + (lane >> 2);
    const int kp    = lane & 3;
    const ushort_t* a0 = A  + (size_t)(m0 + srow0) * K + (size_t)((kp ^ ((srow0 >> 1) & 3)) * 8);
    const ushort_t* a1 = A  + (size_t)(m0 + srow1) * K + (size_t)((kp ^ ((srow1 >> 1) & 3)) * 8);
    const ushort_t* b0 = Bt + (size_t)(n0 + srow0) * K + (size_t)((kp ^ ((srow0 >> 1) & 3)) * 8);
    const ushort_t* b1 = Bt + (size_t)(n0 + srow1) * K + (size_t)((kp ^ ((srow1 >> 1) & 3)) * 8);
    char* asb0 = (char*)As + w * 1024;
    char* asb1 = (char*)As + (w + 4) * 1024;
    char* bsb0 = (char*)Bs + w * 1024;
    char* bsb1 = (char*)Bs + (w + 4) * 1024;

    int aoff[4], boff[4];
    #pragma unroll
    for (int i = 0; i < 4; i++) {
        int ra = wm + i * 16 + l16;
        aoff[i] = ra * 64 + (quad ^ ((ra >> 1) & 3)) * 16;
        int rb = wn + i * 16 + l16;
        boff[i] = rb * 64 + (quad ^ ((rb >> 1) & 3)) * 16;
    }

    float4_ acc[4][4] = {};

    for (int k0 = 0; k0 < K; k0 += 32) {
        __syncthreads();
        GLD_LDS16(a0 + k0, asb0);
        GLD_LDS16(a1 + k0, asb1);
        GLD_LDS16(b0 + k0, bsb0);
        GLD_LDS16(b1 + k0, bsb1);
        __syncthreads();

        short8 af[4], bf[4];
        #pragma unroll
        for (int i = 0; i < 4; i++) af[i] = *(const short8*)((const char*)As + aoff[i]);
        #pragma unroll
        for (int i = 0; i < 4; i++) bf[i] = *(const short8*)((const char*)Bs + boff[i]);
        #pragma unroll
        for (int mi = 0; mi < 4; mi++)
            #pragma unroll
            for (int ni = 0; ni < 4; ni++)
                acc[mi][ni] = MFMA32(af[mi], bf[ni], acc[mi][ni]);
    }

    #pragma unroll
    for (int mi = 0; mi < 4; mi++) {
        int row = m0 + wm + mi * 16 + quad * 4;
        #pragma unroll
        for (int ni = 0; ni < 4; ni++) {
            int col = n0 + wn + ni * 16 + l16;
            float b = bias[col];
            float sc = (SCALE_Q && col < 1024) ? SCL : 1.0f;
            #pragma unroll
            for (int r = 0; r < 4; r++) {
                float v = (acc[mi][ni][r] + b) * sc;
                if (OUT_BF16)
                    ((ushort_t*)C)[(size_t)(row + r) * N + col] = f2bf(v);
                else
                    ((float*)C)[(size_t)(row + r) * N + col] = v;
            }
        }
    }
}

// ---------------- flash attention v3 ----------------
// q-tile 64, k-tile 64. 4 waves; wave w: q-half qh=w>>1 (32 rows), kv-half kh=w&1 (32 rows).
// S^T = K·Q^T (16x16x32), P^T regs feed O^T = V^T·P^T (16x16x16) directly.
// K staged via global_load_lds into XOR-swizzled row-major LDS; V transposed via dword perms.
// kv-partials (O^T, l) combined across wave pairs through LDS at the end.
__global__ __launch_bounds__(256, 4)
void flash_attn_k(const ushort_t* __restrict__ qkv, ushort_t* __restrict__ out) {
    __shared__ char smem[18432];
    ushort_t* Qs   = (ushort_t*)smem;             // prologue only, stride 72
    ushort_t* Vt   = (ushort_t*)(smem + 8192);    // [d][kv], stride 72
    float*    Obuf = (float*)smem;                // epilogue, [64][68]
    float*    lbuf = (float*)(smem + 17408);      // [64][2]

    const int bh = blockIdx.y;
    const int b  = bh >> 4, h = bh & 15;
    const int q0 = blockIdx.x * 64;
    const int tid  = threadIdx.x;
    const int w    = tid >> 6;
    const int lane = tid & 63;
    const int quad = lane >> 4;
    const int l16  = lane & 15;
    const int qh   = w >> 1;   // q-half
    const int kh   = w & 1;    // kv-half

    const size_t tok0 = (size_t)b * 2048;
    const int hq = h * 64;

    // ---- prologue: Q tile [64][64] -> LDS -> register frags ----
    {
        int r = tid >> 2, c = (tid & 3) * 16;
        const ushort_t* src = qkv + (tok0 + q0 + r) * 3072 + hq + c;
        *(float4*)&Qs[r * 72 + c]     = *(const float4*)(src);
        *(float4*)&Qs[r * 72 + c + 8] = *(const float4*)(src + 8);
    }
    __syncthreads();
    short8 qf[2][2];
    #pragma unroll
    for (int sub = 0; sub < 2; sub++)
        #pragma unroll
        for (int kk = 0; kk < 2; kk++)
            qf[sub][kk] = *(const short8*)&Qs[(qh * 32 + sub * 16 + l16) * 72 + kk * 32 + quad * 8];

    // ---- K staging map (global_load_lds, row-major 128B rows, slot ^= (row>>1)&7) ----
    const int rl0 = 16 * w + (lane >> 3);
    const int rl1 = rl0 + 8;
    const int s7  = lane & 7;
    const ushort_t* kp0 = qkv + (tok0 + rl0) * 3072 + 1024 + hq + (size_t)((s7 ^ ((rl0 >> 1) & 7)) * 8);
    const ushort_t* kp1 = qkv + (tok0 + rl1) * 3072 + 1024 + hq + (size_t)((s7 ^ ((rl1 >> 1) & 7)) * 8);
    char* ksb0 = smem + w * 2048;
    char* ksb1 = smem + w * 2048 + 1024;

    // K frag byte offsets: row = kh*32+mi*16+l16, seg=kk*4+quad, slot = seg^((row>>1)&7)
    int koff[2][2];
    #pragma unroll
    for (int mi = 0; mi < 2; mi++)
        #pragma unroll
        for (int kk = 0; kk < 2; kk++) {
            int row = kh * 32 + mi * 16 + l16;
            koff[mi][kk] = row * 128 + (((kk * 4 + quad) ^ ((row >> 1) & 7)) * 16);
        }

    // ---- V transpose staging map ----
    const int pr  = tid & 31;
    const int jj0 = tid >> 5;
    const ushort_t* vb0 = qkv + (tok0 + 2 * pr) * 3072 + 2048 + hq;
    const ushort_t* vb1 = vb0 + 3072;

    float4_ ot[2][4] = {};        // O^T: d = di*16+quad*4+r, q = qh*32+sub*16+l16
    float lsum[2] = {0.f, 0.f};

    for (int kt = 0; kt < 2048; kt += 64) {
        __syncthreads();   // prior tile reads complete
        GLD_LDS16(kp0 + (size_t)kt * 3072, ksb0);
        GLD_LDS16(kp1 + (size_t)kt * 3072, ksb1);
        {   // V transposed via dword perms (b32 writes, conflict-free)
            const ushort_t* s0 = vb0 + (size_t)kt * 3072;
            const ushort_t* s1 = vb1 + (size_t)kt * 3072;
            #pragma unroll
            for (int it = 0; it < 2; it++) {
                int J = jj0 + it * 8;
                uint2 X = *(const uint2*)(s0 + 4 * J);
                uint2 Y = *(const uint2*)(s1 + 4 * J);
                uint32_t_ w0 = (X.x & 0xffffu) | (Y.x << 16);
                uint32_t_ w1 = (X.x >> 16)     | (Y.x & 0xffff0000u);
                uint32_t_ w2 = (X.y & 0xffffu) | (Y.y << 16);
                uint32_t_ w3 = (X.y >> 16)     | (Y.y & 0xffff0000u);
                *(uint32_t_*)&Vt[(4 * J + 0) * 72 + 2 * pr] = w0;
                *(uint32_t_*)&Vt[(4 * J + 1) * 72 + 2 * pr] = w1;
                *(uint32_t_*)&Vt[(4 * J + 2) * 72 + 2 * pr] = w2;
                *(uint32_t_*)&Vt[(4 * J + 3) * 72 + 2 * pr] = w3;
            }
        }
        __syncthreads();

        // S^T: st[mi][sub], kv = kt + kh*32 + mi*16 + quad*4 + r, q = qh*32+sub*16+l16
        float4_ st[2][2];
        #pragma unroll
        for (int mi = 0; mi < 2; mi++) {
            short8 kf0 = *(const short8*)(smem + koff[mi][0]);
            short8 kf1 = *(const short8*)(smem + koff[mi][1]);
            #pragma unroll
            for (int sub = 0; sub < 2; sub++) {
                float4_ z = {0.f, 0.f, 0.f, 0.f};
                z = MFMA32(kf0, qf[sub][0], z);
                z = MFMA32(kf1, qf[sub][1], z);
                st[mi][sub] = z;
            }
        }

        // exp2 (scale folded into Q), accumulate l, pack P^T -> bf16 B-frags
        short4_ bp[2][2];
        #pragma unroll
        for (int sub = 0; sub < 2; sub++)
            #pragma unroll
            for (int mi = 0; mi < 2; mi++) {
                float p0 = __builtin_amdgcn_exp2f(st[mi][sub][0]);
                float p1 = __builtin_amdgcn_exp2f(st[mi][sub][1]);
                float p2 = __builtin_amdgcn_exp2f(st[mi][sub][2]);
                float p3 = __builtin_amdgcn_exp2f(st[mi][sub][3]);
                lsum[sub] += (p0 + p1) + (p2 + p3);
                uint2v d;
                d.x = pack_bf16(p0, p1);
                d.y = pack_bf16(p2, p3);
                bp[sub][mi] = __builtin_bit_cast(short4_, d);
            }

        // O^T += V^T · P^T  (16x16x16; k = wave's kv 16-chunks)
        #pragma unroll
        for (int di = 0; di < 4; di++) {
            short4_ av0 = *(const short4_*)&Vt[(di * 16 + l16) * 72 + kh * 32 + quad * 4];
            short4_ av1 = *(const short4_*)&Vt[(di * 16 + l16) * 72 + kh * 32 + 16 + quad * 4];
            #pragma unroll
            for (int sub = 0; sub < 2; sub++) {
                ot[sub][di] = mfma16x16x16_bf16(av0, bp[sub][0], ot[sub][di]);
                ot[sub][di] = mfma16x16x16_bf16(av1, bp[sub][1], ot[sub][di]);
            }
        }
    }

    // reduce l over quads (each quad holds a kv sub-range)
    #pragma unroll
    for (int sub = 0; sub < 2; sub++) {
        float t = lsum[sub];
        t += __shfl_xor(t, 16, 64);
        t += __shfl_xor(t, 32, 64);
        lsum[sub] = t;
    }

    // ---- combine kv-halves across wave pairs through LDS ----
    __syncthreads();   // all Vt/Ks reads done; safe to overlay Obuf
    #pragma unroll
    for (int sub = 0; sub < 2; sub++)
        lbuf[(qh * 32 + sub * 16 + l16) * 2 + kh] = lsum[sub];
    if (kh == 1) {
        #pragma unroll
        for (int sub = 0; sub < 2; sub++)
            #pragma unroll
            for (int di = 0; di < 4; di++)
                *(float4_*)&Obuf[(qh * 32 + sub * 16 + l16) * 68 + di * 16 + quad * 4] = ot[sub][di];
    }
    __syncthreads();
    if (kh == 0) {
        #pragma unroll
        for (int sub = 0; sub < 2; sub++)
            #pragma unroll
            for (int di = 0; di < 4; di++) {
                float4_* p = (float4_*)&Obuf[(qh * 32 + sub * 16 + l16) * 68 + di * 16 + quad * 4];
                *p = *p + ot[sub][di];
            }
    }
    __syncthreads();

    // ---- normalize + write out ----
    {
        int q  = tid >> 2;
        int ds = (tid & 3) * 16;
        float linv = 1.0f / (lbuf[q * 2] + lbuf[q * 2 + 1]);
        const float* ob = &Obuf[q * 68 + ds];
        uint4v d0, d1;
        float4_ v0 = *(const float4_*)(ob);
        float4_ v1 = *(const float4_*)(ob + 4);
        float4_ v2 = *(const float4_*)(ob + 8);
        float4_ v3 = *(const float4_*)(ob + 12);
        d0.x = pack_bf16(v0[0] * linv, v0[1] * linv);
        d0.y = pack_bf16(v0[2] * linv, v0[3] * linv);
        d0.z = pack_bf16(v1[0] * linv, v1[1] * linv);
        d0.w = pack_bf16(v1[2] * linv, v1[3] * linv);
        d1.x = pack_bf16(v2[0] * linv, v2[1] * linv);
        d1.y = pack_bf16(v2[2] * linv, v2[3] * linv);
        d1.z = pack_bf16(v3[0] * linv, v3[1] * linv);
        d1.w = pack_bf16(v3[2] * linv, v3[3] * linv);
        ushort_t* dst = out + (tok0 + q0 + q) * 1024 + hq + ds;
        *(uint4v*)(dst)     = d0;
        *(uint4v*)(dst + 8) = d1;
    }
}

extern "C" void kernel_launch(void* const* d_in, const int* in_sizes, int n_in,
                              void* d_out, int out_size, void* d_ws, size_t ws_size,
                              hipStream_t stream) {
    const float* x    = (const float*)d_in[0];  // [2,2048,1024]
    const float* Wqkv = (const float*)d_in[1];  // [1024,3072]
    const float* bqkv = (const float*)d_in[2];  // [3072]
    const float* Wout = (const float*)d_in[3];  // [1024,1024]
    const float* bout = (const float*)d_in[4];  // [1024]
    float* out = (float*)d_out;                 // [2,2048,1024] fp32

    char* ws = (char*)d_ws;
    ushort_t* x_bf    = (ushort_t*)(ws);             // 8 MB
    ushort_t* WqkvT   = (ushort_t*)(ws + 8388608);   // 6 MB
    ushort_t* WoutT   = (ushort_t*)(ws + 14680064);  // 2 MB
    ushort_t* qkv_bf  = (ushort_t*)(ws + 16777216);  // 24 MB
    ushort_t* attn_bf = (ushort_t*)(ws + 41943040);  // 8 MB

    cvt_bf16_k<<<4096, 256, 0, stream>>>(x, x_bf, 4096 * 1024);
    transpose_bf16_k<<<dim3(96, 32), 256, 0, stream>>>(Wqkv, WqkvT, 1024, 3072);
    transpose_bf16_k<<<dim3(32, 32), 256, 0, stream>>>(Wout, WoutT, 1024, 1024);

    gemm_bt_k<true, true><<<dim3(24, 32), 256, 0, stream>>>(
        x_bf, WqkvT, bqkv, (void*)qkv_bf, 4096, 3072, 1024);

    flash_attn_k<<<dim3(32, 32), 256, 0, stream>>>(qkv_bf, attn_bf);

    gemm_bt_k<false, false><<<dim3(8, 32), 256, 0, stream>>>(
        attn_bf, WoutT, bout, (void*)out, 4096, 1024, 1024);
}

// Round 4
// 187.576 us; speedup vs baseline: 1.2182x; 1.2182x over previous
//
#include <hip/hip_runtime.h>
#include <hip/hip_bf16.h>

typedef short short8 __attribute__((ext_vector_type(8)));
typedef short short4_ __attribute__((ext_vector_type(4)));
typedef float float4_ __attribute__((ext_vector_type(4)));
typedef unsigned short ushort_t;
typedef unsigned int uint32_t_;
typedef uint32_t_ uint2v __attribute__((ext_vector_type(2)));
typedef uint32_t_ uint4v __attribute__((ext_vector_type(4)));

#define SCL 0.1803368801111f   // log2(e)/sqrt(64), folded into Q via gemm1 epilogue

__device__ __forceinline__ ushort_t f2bf(float f) {
    uint32_t_ u = __builtin_bit_cast(uint32_t_, f);
    u = (u + 0x7fffu + ((u >> 16) & 1u)) >> 16;
    return (ushort_t)u;
}

// pack two floats to bf16x2 (round-half-up on mantissa), a in low half
__device__ __forceinline__ uint32_t_ pack_bf16(float a, float b) {
    uint32_t_ ua = __builtin_bit_cast(uint32_t_, a) + 0x8000u;
    uint32_t_ ub = __builtin_bit_cast(uint32_t_, b) + 0x8000u;
    return __builtin_amdgcn_perm(ub, ua, 0x07060302);
}

__device__ __forceinline__ float4_ mfma16x16x16_bf16(short4_ a, short4_ b, float4_ c) {
#if __has_builtin(__builtin_amdgcn_mfma_f32_16x16x16bf16_1k)
    return __builtin_amdgcn_mfma_f32_16x16x16bf16_1k(a, b, c, 0, 0, 0);
#else
    asm volatile("v_mfma_f32_16x16x16_bf16 %0, %1, %2, %0" : "+v"(c) : "v"(a), "v"(b));
    return c;
#endif
}

#define MFMA32(a, b, c) __builtin_amdgcn_mfma_f32_16x16x32_bf16(a, b, c, 0, 0, 0)

#define GLD_LDS16(g, l) __builtin_amdgcn_global_load_lds( \
    (const __attribute__((address_space(1))) void*)(g),   \
    (__attribute__((address_space(3))) void*)(l), 16, 0, 0)

// ---------------- convert fp32 -> bf16 ----------------
__global__ void cvt_bf16_k(const float* __restrict__ in, ushort_t* __restrict__ out, int n) {
    int i = (blockIdx.x * blockDim.x + threadIdx.x) * 4;
    if (i + 3 < n) {
        float4 v = *(const float4*)(in + i);
        uint32_t_ lo = (uint32_t_)f2bf(v.x) | ((uint32_t_)f2bf(v.y) << 16);
        uint32_t_ hi = (uint32_t_)f2bf(v.z) | ((uint32_t_)f2bf(v.w) << 16);
        *(uint2*)(out + i) = make_uint2(lo, hi);
    }
}

// ---------------- transpose [K][N] fp32 -> [N][K] bf16 ----------------
__global__ void transpose_bf16_k(const float* __restrict__ in, ushort_t* __restrict__ out,
                                 int K, int N) {
    __shared__ float tile[32][33];
    int n0 = blockIdx.x * 32, k0 = blockIdx.y * 32;
    int tx = threadIdx.x & 31, ty = threadIdx.x >> 5;
    #pragma unroll
    for (int i = 0; i < 32; i += 8)
        tile[ty + i][tx] = in[(size_t)(k0 + ty + i) * N + n0 + tx];
    __syncthreads();
    #pragma unroll
    for (int i = 0; i < 32; i += 8)
        out[(size_t)(n0 + ty + i) * K + k0 + tx] = f2bf(tile[tx][ty + i]);
}

// ---------------- double-buffered GEMM: C = A[M][K] @ Bt[N][K]^T + bias ----------------
// BM=128, BK=32, single barrier per k-step, global_load_lds staging, XOR-swizzled LDS.
// QKV_EPI: N=3072 fused epilogue — Q cols (<1024) scaled->qk[tok][2048], K cols->qk,
//          V cols (>=2048) written transuted+permuted to Vt_out[bh*64+d][2048].
template <int TN, bool QKV_EPI>
__global__ __launch_bounds__(256, 2)
void gemm_dbuf_k(const ushort_t* __restrict__ A, const ushort_t* __restrict__ Bt,
                 const float* __restrict__ bias, void* __restrict__ C,
                 ushort_t* __restrict__ Vt_out, int M, int N, int K) {
    constexpr int NB   = TN / 32;           // N acc frags per wave
    constexpr int SETB = 8192 + TN * 64;    // bytes per buffer set
    __shared__ char smem[2 * SETB];
    const int tid  = threadIdx.x;
    const int m0   = blockIdx.y * 128;
    const int n0   = blockIdx.x * TN;
    const int w    = tid >> 6;
    const int lane = tid & 63;
    const int wm   = (w >> 1) * 64;
    const int wn   = (w & 1) * (TN / 2);
    const int quad = lane >> 4;
    const int l16  = lane & 15;

    // staging: 64B rows, 4 lanes/row, 16B chunk slot = seg ^ ((row>>1)&3)
    const int sr = 16 * w + (lane >> 2);
    const int sc = ((lane & 3) ^ ((sr >> 1) & 3)) * 8;
    const ushort_t* ag0 = A  + (size_t)(m0 + sr) * K + sc;
    const ushort_t* ag1 = A  + (size_t)(m0 + sr + 64) * K + sc;
    const ushort_t* bg0 = Bt + (size_t)(n0 + sr) * K + sc;
    const ushort_t* bg1 = Bt + (size_t)(n0 + sr + 64) * K + sc;   // TN==128 only
    char* sA = smem + 1024 * w;
    char* sB = smem + 8192 + 1024 * w;

    int aoff[4], boff[NB];
    #pragma unroll
    for (int i = 0; i < 4; i++) {
        int row = wm + i * 16 + l16;
        aoff[i] = row * 64 + ((quad ^ ((row >> 1) & 3)) * 16);
    }
    #pragma unroll
    for (int i = 0; i < NB; i++) {
        int row = wn + i * 16 + l16;
        boff[i] = 8192 + row * 64 + ((quad ^ ((row >> 1) & 3)) * 16);
    }

    float4_ acc[4][NB] = {};
    const int NIT = K >> 5;

    GLD_LDS16(ag0, sA);
    GLD_LDS16(ag1, sA + 4096);
    GLD_LDS16(bg0, sB);
    if (TN == 128) GLD_LDS16(bg1, sB + 4096);

    for (int it = 0; it < NIT; ++it) {
        __syncthreads();                       // drains DMA(it); all prior frag reads done
        if (it + 1 < NIT) {
            const int nk = (it + 1) * 32;
            char* dA = sA + ((it + 1) & 1) * SETB;
            char* dB = sB + ((it + 1) & 1) * SETB;
            GLD_LDS16(ag0 + nk, dA);
            GLD_LDS16(ag1 + nk, dA + 4096);
            GLD_LDS16(bg0 + nk, dB);
            if (TN == 128) GLD_LDS16(bg1 + nk, dB + 4096);
        }
        const char* base = smem + (it & 1) * SETB;
        short8 af[4], bf[NB];
        #pragma unroll
        for (int i = 0; i < 4; i++)  af[i] = *(const short8*)(base + aoff[i]);
        #pragma unroll
        for (int i = 0; i < NB; i++) bf[i] = *(const short8*)(base + boff[i]);
        #pragma unroll
        for (int mi = 0; mi < 4; mi++)
            #pragma unroll
            for (int ni = 0; ni < NB; ni++)
                acc[mi][ni] = MFMA32(af[mi], bf[ni], acc[mi][ni]);
    }

    #pragma unroll
    for (int mi = 0; mi < 4; mi++) {
        int row = m0 + wm + mi * 16 + quad * 4;
        #pragma unroll
        for (int ni = 0; ni < NB; ni++) {
            int col = n0 + wn + ni * 16 + l16;
            float bb = bias[col];
            if (QKV_EPI) {
                if (col < 2048) {
                    float sc2 = (col < 1024) ? SCL : 1.0f;
                    #pragma unroll
                    for (int r = 0; r < 4; r++)
                        ((ushort_t*)C)[(size_t)(row + r) * 2048 + col] =
                            f2bf((acc[mi][ni][r] + bb) * sc2);
                } else {
                    // V^T permuted: s' = (s&~31) | quad*8 | (mi&1)*4 | r
                    int s0v  = row & 2047;
                    int spos = (s0v & ~31) | (quad << 3) | ((mi & 1) << 2);
                    size_t vrow = (size_t)((row >> 11) * 1024 + (col - 2048));
                    float v0 = acc[mi][ni][0] + bb, v1 = acc[mi][ni][1] + bb;
                    float v2 = acc[mi][ni][2] + bb, v3 = acc[mi][ni][3] + bb;
                    uint2v pk;
                    pk.x = pack_bf16(v0, v1);
                    pk.y = pack_bf16(v2, v3);
                    *(uint2v*)(Vt_out + vrow * 2048 + spos) = pk;
                }
            } else {
                #pragma unroll
                for (int r = 0; r < 4; r++)
                    ((float*)C)[(size_t)(row + r) * N + col] = acc[mi][ni][r] + bb;
            }
        }
    }
}

// ---------------- flash attention v4: DMA-staged, double-buffered, 1 barrier/tile ----
// qk bf16 [tok][2048] = [q(1024,pre-scaled) | k(1024)]; vt bf16 [bh*64+d][2048] s-permuted.
// q-tile 64, kv-tile 64; 4 waves: qh=w>>1 (32 q), kh=w&1 (32 kv).
// S^T = K·Q^T (16x16x32); P^T regs feed O^T = V^T·P^T (16x16x16) directly.
__global__ __launch_bounds__(256, 4)
void flash_attn_k(const ushort_t* __restrict__ qk, const ushort_t* __restrict__ vt,
                  ushort_t* __restrict__ out) {
    __shared__ char smem[32768];   // B0: K@0,V@8192 ; B1: K@16384,V@24576 (Q prologue in B1.K)
    const int bh = blockIdx.y;
    const int b  = bh >> 4, h = bh & 15;
    const int q0 = blockIdx.x * 64;
    const int tid  = threadIdx.x;
    const int w    = tid >> 6;
    const int lane = tid & 63;
    const int quad = lane >> 4;
    const int l16  = lane & 15;
    const int qh   = w >> 1;
    const int kh   = w & 1;
    const size_t tok0 = (size_t)b * 2048;
    const int hq = h * 64;

    // staging maps: 128B rows, 8 lanes/row, chunk slot = s7 ^ ((row>>1)&7)
    const int r0 = 16 * w + (lane >> 3), r1 = r0 + 8;
    const int s7 = lane & 7;
    const int c0 = (s7 ^ ((r0 >> 1) & 7)) * 8;
    const int c1 = (s7 ^ ((r1 >> 1) & 7)) * 8;
    const ushort_t* qg0 = qk + (tok0 + q0 + r0) * 2048 + hq + c0;
    const ushort_t* qg1 = qk + (tok0 + q0 + r1) * 2048 + hq + c1;
    const ushort_t* kg0 = qk + (tok0 + r0) * 2048 + 1024 + hq + c0;
    const ushort_t* kg1 = qk + (tok0 + r1) * 2048 + 1024 + hq + c1;
    const ushort_t* vg0 = vt + (size_t)(bh * 64 + r0) * 2048 + c0;
    const ushort_t* vg1 = vt + (size_t)(bh * 64 + r1) * 2048 + c1;
    char* stK = smem + 2048 * w;
    char* stV = smem + 8192 + 2048 * w;
    char* stQ = smem + 16384 + 2048 * w;

    // prologue: Q -> B1.K area; K0/V0 -> B0
    GLD_LDS16(qg0, stQ);
    GLD_LDS16(qg1, stQ + 1024);
    GLD_LDS16(kg0, stK);
    GLD_LDS16(kg1, stK + 1024);
    GLD_LDS16(vg0, stV);
    GLD_LDS16(vg1, stV + 1024);
    __syncthreads();

    const int sw = (l16 >> 1) & 7;   // row-swizzle term for all frag reads
    short8 qf[2][2];
    #pragma unroll
    for (int sub = 0; sub < 2; sub++)
        #pragma unroll
        for (int kk = 0; kk < 2; kk++) {
            int row = qh * 32 + sub * 16 + l16;
            qf[sub][kk] = *(const short8*)(smem + 16384 + row * 128 +
                                           (((kk * 4 + quad) ^ sw) * 16));
        }

    int koff[2][2], voff[4];
    #pragma unroll
    for (int mi = 0; mi < 2; mi++)
        #pragma unroll
        for (int kk = 0; kk < 2; kk++) {
            int row = kh * 32 + mi * 16 + l16;
            koff[mi][kk] = row * 128 + (((kk * 4 + quad) ^ sw) * 16);
        }
    #pragma unroll
    for (int di = 0; di < 4; di++) {
        int row = di * 16 + l16;
        voff[di] = 8192 + row * 128 + (((kh * 4 + quad) ^ sw) * 16);
    }

    float4_ ot[2][4] = {};        // O^T: d = di*16+quad*4+r, q = qh*32+sub*16+l16
    float lsum[2] = {0.f, 0.f};

    for (int kt = 0; kt < 2048; kt += 64) {
        __syncthreads();          // drains DMA(kt); prior-tile + Q frag reads all done
        const int set = (kt >> 6) & 1;
        if (kt + 64 < 2048) {
            const int nb = (set ^ 1) * 16384;
            const size_t go = (size_t)(kt + 64);
            GLD_LDS16(kg0 + go * 2048, stK + nb);
            GLD_LDS16(kg1 + go * 2048, stK + nb + 1024);
            GLD_LDS16(vg0 + go, stV + nb);
            GLD_LDS16(vg1 + go, stV + nb + 1024);
        }
        const char* base = smem + set * 16384;

        // S^T: kv = kt + kh*32 + mi*16 + quad*4 + r, q = qh*32 + sub*16 + l16
        float4_ st[2][2];
        #pragma unroll
        for (int mi = 0; mi < 2; mi++) {
            short8 kf0 = *(const short8*)(base + koff[mi][0]);
            short8 kf1 = *(const short8*)(base + koff[mi][1]);
            #pragma unroll
            for (int sub = 0; sub < 2; sub++) {
                float4_ z = {0.f, 0.f, 0.f, 0.f};
                z = MFMA32(kf0, qf[sub][0], z);
                z = MFMA32(kf1, qf[sub][1], z);
                st[mi][sub] = z;
            }
        }

        // exp2 (scale folded into Q), accumulate l, pack P^T -> bf16 B-frags
        short4_ bp[2][2];
        #pragma unroll
        for (int sub = 0; sub < 2; sub++)
            #pragma unroll
            for (int mi = 0; mi < 2; mi++) {
                float p0 = __builtin_amdgcn_exp2f(st[mi][sub][0]);
                float p1 = __builtin_amdgcn_exp2f(st[mi][sub][1]);
                float p2 = __builtin_amdgcn_exp2f(st[mi][sub][2]);
                float p3 = __builtin_amdgcn_exp2f(st[mi][sub][3]);
                lsum[sub] += (p0 + p1) + (p2 + p3);
                uint2v d;
                d.x = pack_bf16(p0, p1);
                d.y = pack_bf16(p2, p3);
                bp[sub][mi] = __builtin_bit_cast(short4_, d);
            }

        // O^T += V^T · P^T  (16x16x16); vv b128 covers both 16-kv chunks of wave's half
        #pragma unroll
        for (int di = 0; di < 4; di++) {
            short8 vv = *(const short8*)(base + voff[di]);
            short4_ av0 = __builtin_shufflevector(vv, vv, 0, 1, 2, 3);
            short4_ av1 = __builtin_shufflevector(vv, vv, 4, 5, 6, 7);
            #pragma unroll
            for (int sub = 0; sub < 2; sub++) {
                ot[sub][di] = mfma16x16x16_bf16(av0, bp[sub][0], ot[sub][di]);
                ot[sub][di] = mfma16x16x16_bf16(av1, bp[sub][1], ot[sub][di]);
            }
        }
    }

    // reduce l over quads
    #pragma unroll
    for (int sub = 0; sub < 2; sub++) {
        float t = lsum[sub];
        t += __shfl_xor(t, 16, 64);
        t += __shfl_xor(t, 32, 64);
        lsum[sub] = t;
    }

    // combine kv-halves across wave pairs through LDS (overlay on buffers)
    float* Obuf = (float*)smem;                 // [64][68]
    float* lbuf = (float*)(smem + 17408);       // [64][2]
    __syncthreads();                            // all buffer reads done
    #pragma unroll
    for (int sub = 0; sub < 2; sub++)
        lbuf[(qh * 32 + sub * 16 + l16) * 2 + kh] = lsum[sub];
    if (kh == 1) {
        #pragma unroll
        for (int sub = 0; sub < 2; sub++)
            #pragma unroll
            for (int di = 0; di < 4; di++)
                *(float4_*)&Obuf[(qh * 32 + sub * 16 + l16) * 68 + di * 16 + quad * 4] = ot[sub][di];
    }
    __syncthreads();
    if (kh == 0) {
        #pragma unroll
        for (int sub = 0; sub < 2; sub++)
            #pragma unroll
            for (int di = 0; di < 4; di++) {
                float4_* p = (float4_*)&Obuf[(qh * 32 + sub * 16 + l16) * 68 + di * 16 + quad * 4];
                *p = *p + ot[sub][di];
            }
    }
    __syncthreads();

    // normalize + coalesced store
    {
        int q  = tid >> 2;
        int ds = (tid & 3) * 16;
        float linv = 1.0f / (lbuf[q * 2] + lbuf[q * 2 + 1]);
        const float* ob = &Obuf[q * 68 + ds];
        float4_ v0 = *(const float4_*)(ob);
        float4_ v1 = *(const float4_*)(ob + 4);
        float4_ v2 = *(const float4_*)(ob + 8);
        float4_ v3 = *(const float4_*)(ob + 12);
        uint4v d0, d1;
        d0.x = pack_bf16(v0[0] * linv, v0[1] * linv);
        d0.y = pack_bf16(v0[2] * linv, v0[3] * linv);
        d0.z = pack_bf16(v1[0] * linv, v1[1] * linv);
        d0.w = pack_bf16(v1[2] * linv, v1[3] * linv);
        d1.x = pack_bf16(v2[0] * linv, v2[1] * linv);
        d1.y = pack_bf16(v2[2] * linv, v2[3] * linv);
        d1.z = pack_bf16(v3[0] * linv, v3[1] * linv);
        d1.w = pack_bf16(v3[2] * linv, v3[3] * linv);
        ushort_t* dst = out + (tok0 + q0 + (size_t)q) * 1024 + hq + ds;
        *(uint4v*)(dst)     = d0;
        *(uint4v*)(dst + 8) = d1;
    }
}

extern "C" void kernel_launch(void* const* d_in, const int* in_sizes, int n_in,
                              void* d_out, int out_size, void* d_ws, size_t ws_size,
                              hipStream_t stream) {
    const float* x    = (const float*)d_in[0];  // [2,2048,1024]
    const float* Wqkv = (const float*)d_in[1];  // [1024,3072]
    const float* bqkv = (const float*)d_in[2];  // [3072]
    const float* Wout = (const float*)d_in[3];  // [1024,1024]
    const float* bout = (const float*)d_in[4];  // [1024]
    float* out = (float*)d_out;                 // [2,2048,1024] fp32

    char* ws = (char*)d_ws;
    ushort_t* x_bf    = (ushort_t*)(ws);             // 8 MB
    ushort_t* WqkvT   = (ushort_t*)(ws + 8388608);   // 6 MB
    ushort_t* WoutT   = (ushort_t*)(ws + 14680064);  // 2 MB
    ushort_t* qk_bf   = (ushort_t*)(ws + 16777216);  // [4096][2048] = 16 MB
    ushort_t* vt_bf   = (ushort_t*)(ws + 33554432);  // [2048][2048] = 8 MB
    ushort_t* attn_bf = (ushort_t*)(ws + 41943040);  // 8 MB

    cvt_bf16_k<<<4096, 256, 0, stream>>>(x, x_bf, 4096 * 1024);
    transpose_bf16_k<<<dim3(96, 32), 256, 0, stream>>>(Wqkv, WqkvT, 1024, 3072);
    transpose_bf16_k<<<dim3(32, 32), 256, 0, stream>>>(Wout, WoutT, 1024, 1024);

    gemm_dbuf_k<128, true><<<dim3(24, 32), 256, 0, stream>>>(
        x_bf, WqkvT, bqkv, (void*)qk_bf, vt_bf, 4096, 3072, 1024);

    flash_attn_k<<<dim3(32, 32), 256, 0, stream>>>(qk_bf, vt_bf, attn_bf);

    gemm_dbuf_k<64, false><<<dim3(16, 32), 256, 0, stream>>>(
        attn_bf, WoutT, bout, (void*)out, nullptr, 4096, 1024, 1024);
}

// Round 5
// 182.771 us; speedup vs baseline: 1.2502x; 1.0263x over previous
//
#include <hip/hip_runtime.h>
#include <hip/hip_bf16.h>

typedef short short8 __attribute__((ext_vector_type(8)));
typedef short short4_ __attribute__((ext_vector_type(4)));
typedef float float4_ __attribute__((ext_vector_type(4)));
typedef unsigned short ushort_t;
typedef unsigned int uint32_t_;
typedef uint32_t_ uint2v __attribute__((ext_vector_type(2)));
typedef uint32_t_ uint4v __attribute__((ext_vector_type(4)));

#define SCL 0.1803368801111f   // log2(e)/sqrt(64), folded into Q via gemm1 epilogue

__device__ __forceinline__ ushort_t f2bf(float f) {
    uint32_t_ u = __builtin_bit_cast(uint32_t_, f);
    u = (u + 0x7fffu + ((u >> 16) & 1u)) >> 16;
    return (ushort_t)u;
}

// pack two floats to bf16x2 (round-half-up on mantissa), a in low half
__device__ __forceinline__ uint32_t_ pack_bf16(float a, float b) {
    uint32_t_ ua = __builtin_bit_cast(uint32_t_, a) + 0x8000u;
    uint32_t_ ub = __builtin_bit_cast(uint32_t_, b) + 0x8000u;
    return __builtin_amdgcn_perm(ub, ua, 0x07060302);
}

__device__ __forceinline__ float4_ mfma16x16x16_bf16(short4_ a, short4_ b, float4_ c) {
#if __has_builtin(__builtin_amdgcn_mfma_f32_16x16x16bf16_1k)
    return __builtin_amdgcn_mfma_f32_16x16x16bf16_1k(a, b, c, 0, 0, 0);
#else
    asm volatile("v_mfma_f32_16x16x16_bf16 %0, %1, %2, %0" : "+v"(c) : "v"(a), "v"(b));
    return c;
#endif
}

#define MFMA32(a, b, c) __builtin_amdgcn_mfma_f32_16x16x32_bf16(a, b, c, 0, 0, 0)

#define GLD_LDS16(g, l) __builtin_amdgcn_global_load_lds( \
    (const __attribute__((address_space(1))) void*)(g),   \
    (__attribute__((address_space(3))) void*)(l), 16, 0, 0)

// ---------------- merged prep: cvt x + transpose Wqkv + transpose Wout ----------------
// blocks 0..4095: cvt x (fp32->bf16); 4096..7167: Wqkv [1024][3072] -> [3072][1024];
// 7168..8191: Wout [1024][1024] -> [1024][1024].
__global__ __launch_bounds__(256)
void prep_k(const float* __restrict__ x, ushort_t* __restrict__ x_bf,
            const float* __restrict__ Wqkv, ushort_t* __restrict__ WqkvT,
            const float* __restrict__ Wout, ushort_t* __restrict__ WoutT) {
    __shared__ float tile[32][33];
    const int id = blockIdx.x;
    const int tid = threadIdx.x;
    if (id < 4096) {
        int i = (id * 256 + tid) * 4;
        float4 v = *(const float4*)(x + i);
        uint32_t_ lo = (uint32_t_)f2bf(v.x) | ((uint32_t_)f2bf(v.y) << 16);
        uint32_t_ hi = (uint32_t_)f2bf(v.z) | ((uint32_t_)f2bf(v.w) << 16);
        *(uint2*)(x_bf + i) = make_uint2(lo, hi);
        return;
    }
    const float* in;
    ushort_t* out;
    int N, K, n0, k0;
    if (id < 7168) {
        int t = id - 4096;
        in = Wqkv; out = WqkvT; N = 3072; K = 1024;
        n0 = (t % 96) * 32; k0 = (t / 96) * 32;
    } else {
        int t = id - 7168;
        in = Wout; out = WoutT; N = 1024; K = 1024;
        n0 = (t & 31) * 32; k0 = (t >> 5) * 32;
    }
    int tx = tid & 31, ty = tid >> 5;
    #pragma unroll
    for (int i = 0; i < 32; i += 8)
        tile[ty + i][tx] = in[(size_t)(k0 + ty + i) * N + n0 + tx];
    __syncthreads();
    #pragma unroll
    for (int i = 0; i < 32; i += 8)
        out[(size_t)(n0 + ty + i) * K + k0 + tx] = f2bf(tile[tx][ty + i]);
}

// ---------------- double-buffered GEMM: C = A[M][K] @ Bt[N][K]^T + bias ----------------
// BM=128, BK=32, single barrier per k-step, global_load_lds staging, XOR-swizzled LDS.
// QKV_EPI: N=3072 fused epilogue — Q cols (<1024) scaled->qk[tok][2048], K cols->qk,
//          V cols (>=2048) written transposed+permuted to Vt_out[bh*64+d][2048].
template <int TN, bool QKV_EPI>
__global__ __launch_bounds__(256, TN == 128 ? 3 : 4)
void gemm_dbuf_k(const ushort_t* __restrict__ A, const ushort_t* __restrict__ Bt,
                 const float* __restrict__ bias, void* __restrict__ C,
                 ushort_t* __restrict__ Vt_out, int M, int N, int K) {
    constexpr int NB   = TN / 32;           // N acc frags per wave
    constexpr int SETB = 8192 + TN * 64;    // bytes per buffer set
    __shared__ char smem[2 * SETB];
    const int tid  = threadIdx.x;
    const int m0   = blockIdx.y * 128;
    const int n0   = blockIdx.x * TN;
    const int w    = tid >> 6;
    const int lane = tid & 63;
    const int wm   = (w >> 1) * 64;
    const int wn   = (w & 1) * (TN / 2);
    const int quad = lane >> 4;
    const int l16  = lane & 15;

    // staging: 64B rows, 4 lanes/row, 16B chunk slot = seg ^ ((row>>1)&3)
    const int sr = 16 * w + (lane >> 2);
    const int sc = ((lane & 3) ^ ((sr >> 1) & 3)) * 8;
    const ushort_t* ag0 = A  + (size_t)(m0 + sr) * K + sc;
    const ushort_t* ag1 = A  + (size_t)(m0 + sr + 64) * K + sc;
    const ushort_t* bg0 = Bt + (size_t)(n0 + sr) * K + sc;
    const ushort_t* bg1 = Bt + (size_t)(n0 + sr + 64) * K + sc;   // TN==128 only
    char* sA = smem + 1024 * w;
    char* sB = smem + 8192 + 1024 * w;

    int aoff[4], boff[NB];
    #pragma unroll
    for (int i = 0; i < 4; i++) {
        int row = wm + i * 16 + l16;
        aoff[i] = row * 64 + ((quad ^ ((row >> 1) & 3)) * 16);
    }
    #pragma unroll
    for (int i = 0; i < NB; i++) {
        int row = wn + i * 16 + l16;
        boff[i] = 8192 + row * 64 + ((quad ^ ((row >> 1) & 3)) * 16);
    }

    float4_ acc[4][NB] = {};
    const int NIT = K >> 5;

    GLD_LDS16(ag0, sA);
    GLD_LDS16(ag1, sA + 4096);
    GLD_LDS16(bg0, sB);
    if (TN == 128) GLD_LDS16(bg1, sB + 4096);

    for (int it = 0; it < NIT; ++it) {
        __syncthreads();                       // drains DMA(it); all prior frag reads done
        if (it + 1 < NIT) {
            const int nk = (it + 1) * 32;
            char* dA = sA + ((it + 1) & 1) * SETB;
            char* dB = sB + ((it + 1) & 1) * SETB;
            GLD_LDS16(ag0 + nk, dA);
            GLD_LDS16(ag1 + nk, dA + 4096);
            GLD_LDS16(bg0 + nk, dB);
            if (TN == 128) GLD_LDS16(bg1 + nk, dB + 4096);
        }
        const char* base = smem + (it & 1) * SETB;
        short8 af[4], bf[NB];
        #pragma unroll
        for (int i = 0; i < 4; i++)  af[i] = *(const short8*)(base + aoff[i]);
        #pragma unroll
        for (int i = 0; i < NB; i++) bf[i] = *(const short8*)(base + boff[i]);
        #pragma unroll
        for (int mi = 0; mi < 4; mi++)
            #pragma unroll
            for (int ni = 0; ni < NB; ni++)
                acc[mi][ni] = MFMA32(af[mi], bf[ni], acc[mi][ni]);
    }

    #pragma unroll
    for (int mi = 0; mi < 4; mi++) {
        int row = m0 + wm + mi * 16 + quad * 4;
        #pragma unroll
        for (int ni = 0; ni < NB; ni++) {
            int col = n0 + wn + ni * 16 + l16;
            float bb = bias[col];
            if (QKV_EPI) {
                if (col < 2048) {
                    float sc2 = (col < 1024) ? SCL : 1.0f;
                    #pragma unroll
                    for (int r = 0; r < 4; r++)
                        ((ushort_t*)C)[(size_t)(row + r) * 2048 + col] =
                            f2bf((acc[mi][ni][r] + bb) * sc2);
                } else {
                    // V^T permuted: s' = (s&~31) | quad*8 | (mi&1)*4 | r
                    int s0v  = row & 2047;
                    int spos = (s0v & ~31) | (quad << 3) | ((mi & 1) << 2);
                    size_t vrow = (size_t)((row >> 11) * 1024 + (col - 2048));
                    float v0 = acc[mi][ni][0] + bb, v1 = acc[mi][ni][1] + bb;
                    float v2 = acc[mi][ni][2] + bb, v3 = acc[mi][ni][3] + bb;
                    uint2v pk;
                    pk.x = pack_bf16(v0, v1);
                    pk.y = pack_bf16(v2, v3);
                    *(uint2v*)(Vt_out + vrow * 2048 + spos) = pk;
                }
            } else {
                #pragma unroll
                for (int r = 0; r < 4; r++)
                    ((float*)C)[(size_t)(row + r) * N + col] = acc[mi][ni][r] + bb;
            }
        }
    }
}

// ---------------- flash attention v5: DMA-staged, dbuf, 5 blocks/CU, XCD-local bh ----
// qk bf16 [tok][2048] = [q(1024,pre-scaled) | k(1024)]; vt bf16 [bh*64+d][2048] s-permuted.
// grid.x = bh (32) so same-bh blocks stay on one XCD (L2-local K/V); grid.y = q-tile.
// q-tile 64, kv-tile 64; 4 waves: qh=w>>1 (32 q), kh=w&1 (32 kv).
// S^T = K·Q^T (16x16x32); P^T regs feed O^T = V^T·P^T (16x16x16) directly.
__global__ __launch_bounds__(256, 5)
void flash_attn_k(const ushort_t* __restrict__ qk, const ushort_t* __restrict__ vt,
                  ushort_t* __restrict__ out) {
    __shared__ char smem[32768];   // B0: K@0,V@8192 ; B1: K@16384,V@24576 (Q prologue in B1.K)
    const int bh = blockIdx.x;
    const int b  = bh >> 4, h = bh & 15;
    const int q0 = blockIdx.y * 64;
    const int tid  = threadIdx.x;
    const int w    = tid >> 6;
    const int lane = tid & 63;
    const int quad = lane >> 4;
    const int l16  = lane & 15;
    const int qh   = w >> 1;
    const int kh   = w & 1;
    const size_t tok0 = (size_t)b * 2048;
    const int hq = h * 64;

    // staging maps: 128B rows, 8 lanes/row, chunk slot = s7 ^ ((row>>1)&7)
    const int r0 = 16 * w + (lane >> 3), r1 = r0 + 8;
    const int s7 = lane & 7;
    const int c0 = (s7 ^ ((r0 >> 1) & 7)) * 8;
    const int c1 = (s7 ^ ((r1 >> 1) & 7)) * 8;
    const ushort_t* qg0 = qk + (tok0 + q0 + r0) * 2048 + hq + c0;
    const ushort_t* qg1 = qk + (tok0 + q0 + r1) * 2048 + hq + c1;
    const ushort_t* kg0 = qk + (tok0 + r0) * 2048 + 1024 + hq + c0;
    const ushort_t* kg1 = qk + (tok0 + r1) * 2048 + 1024 + hq + c1;
    const ushort_t* vg0 = vt + (size_t)(bh * 64 + r0) * 2048 + c0;
    const ushort_t* vg1 = vt + (size_t)(bh * 64 + r1) * 2048 + c1;
    char* stK = smem + 2048 * w;
    char* stV = smem + 8192 + 2048 * w;
    char* stQ = smem + 16384 + 2048 * w;

    // prologue: Q -> B1.K area; K0/V0 -> B0
    GLD_LDS16(qg0, stQ);
    GLD_LDS16(qg1, stQ + 1024);
    GLD_LDS16(kg0, stK);
    GLD_LDS16(kg1, stK + 1024);
    GLD_LDS16(vg0, stV);
    GLD_LDS16(vg1, stV + 1024);
    __syncthreads();

    const int sw = (l16 >> 1) & 7;   // row-swizzle term for all frag reads
    short8 qf[2][2];
    #pragma unroll
    for (int sub = 0; sub < 2; sub++)
        #pragma unroll
        for (int kk = 0; kk < 2; kk++) {
            int row = qh * 32 + sub * 16 + l16;
            qf[sub][kk] = *(const short8*)(smem + 16384 + row * 128 +
                                           (((kk * 4 + quad) ^ sw) * 16));
        }

    int koff[2][2], voff[4];
    #pragma unroll
    for (int mi = 0; mi < 2; mi++)
        #pragma unroll
        for (int kk = 0; kk < 2; kk++) {
            int row = kh * 32 + mi * 16 + l16;
            koff[mi][kk] = row * 128 + (((kk * 4 + quad) ^ sw) * 16);
        }
    #pragma unroll
    for (int di = 0; di < 4; di++) {
        int row = di * 16 + l16;
        voff[di] = 8192 + row * 128 + (((kh * 4 + quad) ^ sw) * 16);
    }

    float4_ ot[2][4] = {};        // O^T: d = di*16+quad*4+r, q = qh*32+sub*16+l16
    float lsum[2] = {0.f, 0.f};

    for (int kt = 0; kt < 2048; kt += 64) {
        __syncthreads();          // drains DMA(kt); prior-tile + Q frag reads all done
        const int set = (kt >> 6) & 1;
        if (kt + 64 < 2048) {
            const int nb = (set ^ 1) * 16384;
            const size_t go = (size_t)(kt + 64);
            GLD_LDS16(kg0 + go * 2048, stK + nb);
            GLD_LDS16(kg1 + go * 2048, stK + nb + 1024);
            GLD_LDS16(vg0 + go, stV + nb);
            GLD_LDS16(vg1 + go, stV + nb + 1024);
        }
        const char* base = smem + set * 16384;

        // S^T: kv = kt + kh*32 + mi*16 + quad*4 + r, q = qh*32 + sub*16 + l16
        float4_ st[2][2];
        #pragma unroll
        for (int mi = 0; mi < 2; mi++) {
            short8 kf0 = *(const short8*)(base + koff[mi][0]);
            short8 kf1 = *(const short8*)(base + koff[mi][1]);
            #pragma unroll
            for (int sub = 0; sub < 2; sub++) {
                float4_ z = {0.f, 0.f, 0.f, 0.f};
                z = MFMA32(kf0, qf[sub][0], z);
                z = MFMA32(kf1, qf[sub][1], z);
                st[mi][sub] = z;
            }
        }

        // exp2 (scale folded into Q), accumulate l, pack P^T -> bf16 B-frags
        short4_ bp[2][2];
        #pragma unroll
        for (int sub = 0; sub < 2; sub++)
            #pragma unroll
            for (int mi = 0; mi < 2; mi++) {
                float p0 = __builtin_amdgcn_exp2f(st[mi][sub][0]);
                float p1 = __builtin_amdgcn_exp2f(st[mi][sub][1]);
                float p2 = __builtin_amdgcn_exp2f(st[mi][sub][2]);
                float p3 = __builtin_amdgcn_exp2f(st[mi][sub][3]);
                lsum[sub] += (p0 + p1) + (p2 + p3);
                uint2v d;
                d.x = pack_bf16(p0, p1);
                d.y = pack_bf16(p2, p3);
                bp[sub][mi] = __builtin_bit_cast(short4_, d);
            }

        // O^T += V^T · P^T  (16x16x16); vv b128 covers both 16-kv chunks of wave's half
        #pragma unroll
        for (int di = 0; di < 4; di++) {
            short8 vv = *(const short8*)(base + voff[di]);
            short4_ av0 = __builtin_shufflevector(vv, vv, 0, 1, 2, 3);
            short4_ av1 = __builtin_shufflevector(vv, vv, 4, 5, 6, 7);
            #pragma unroll
            for (int sub = 0; sub < 2; sub++) {
                ot[sub][di] = mfma16x16x16_bf16(av0, bp[sub][0], ot[sub][di]);
                ot[sub][di] = mfma16x16x16_bf16(av1, bp[sub][1], ot[sub][di]);
            }
        }
    }

    // reduce l over quads
    #pragma unroll
    for (int sub = 0; sub < 2; sub++) {
        float t = lsum[sub];
        t += __shfl_xor(t, 16, 64);
        t += __shfl_xor(t, 32, 64);
        lsum[sub] = t;
    }

    // combine kv-halves across wave pairs through LDS (overlay on buffers)
    float* Obuf = (float*)smem;                 // [64][68]
    float* lbuf = (float*)(smem + 17408);       // [64][2]
    __syncthreads();                            // all buffer reads done
    #pragma unroll
    for (int sub = 0; sub < 2; sub++)
        lbuf[(qh * 32 + sub * 16 + l16) * 2 + kh] = lsum[sub];
    if (kh == 1) {
        #pragma unroll
        for (int sub = 0; sub < 2; sub++)
            #pragma unroll
            for (int di = 0; di < 4; di++)
                *(float4_*)&Obuf[(qh * 32 + sub * 16 + l16) * 68 + di * 16 + quad * 4] = ot[sub][di];
    }
    __syncthreads();
    if (kh == 0) {
        #pragma unroll
        for (int sub = 0; sub < 2; sub++)
            #pragma unroll
            for (int di = 0; di < 4; di++) {
                float4_* p = (float4_*)&Obuf[(qh * 32 + sub * 16 + l16) * 68 + di * 16 + quad * 4];
                *p = *p + ot[sub][di];
            }
    }
    __syncthreads();

    // normalize + coalesced store
    {
        int q  = tid >> 2;
        int ds = (tid & 3) * 16;
        float linv = 1.0f / (lbuf[q * 2] + lbuf[q * 2 + 1]);
        const float* ob = &Obuf[q * 68 + ds];
        float4_ v0 = *(const float4_*)(ob);
        float4_ v1 = *(const float4_*)(ob + 4);
        float4_ v2 = *(const float4_*)(ob + 8);
        float4_ v3 = *(const float4_*)(ob + 12);
        uint4v d0, d1;
        d0.x = pack_bf16(v0[0] * linv, v0[1] * linv);
        d0.y = pack_bf16(v0[2] * linv, v0[3] * linv);
        d0.z = pack_bf16(v1[0] * linv, v1[1] * linv);
        d0.w = pack_bf16(v1[2] * linv, v1[3] * linv);
        d1.x = pack_bf16(v2[0] * linv, v2[1] * linv);
        d1.y = pack_bf16(v2[2] * linv, v2[3] * linv);
        d1.z = pack_bf16(v3[0] * linv, v3[1] * linv);
        d1.w = pack_bf16(v3[2] * linv, v3[3] * linv);
        ushort_t* dst = out + (tok0 + q0 + (size_t)q) * 1024 + hq + ds;
        *(uint4v*)(dst)     = d0;
        *(uint4v*)(dst + 8) = d1;
    }
}

extern "C" void kernel_launch(void* const* d_in, const int* in_sizes, int n_in,
                              void* d_out, int out_size, void* d_ws, size_t ws_size,
                              hipStream_t stream) {
    const float* x    = (const float*)d_in[0];  // [2,2048,1024]
    const float* Wqkv = (const float*)d_in[1];  // [1024,3072]
    const float* bqkv = (const float*)d_in[2];  // [3072]
    const float* Wout = (const float*)d_in[3];  // [1024,1024]
    const float* bout = (const float*)d_in[4];  // [1024]
    float* out = (float*)d_out;                 // [2,2048,1024] fp32

    char* ws = (char*)d_ws;
    ushort_t* x_bf    = (ushort_t*)(ws);             // 8 MB
    ushort_t* WqkvT   = (ushort_t*)(ws + 8388608);   // 6 MB
    ushort_t* WoutT   = (ushort_t*)(ws + 14680064);  // 2 MB
    ushort_t* qk_bf   = (ushort_t*)(ws + 16777216);  // [4096][2048] = 16 MB
    ushort_t* vt_bf   = (ushort_t*)(ws + 33554432);  // [2048][2048] = 8 MB
    ushort_t* attn_bf = (ushort_t*)(ws + 41943040);  // 8 MB

    prep_k<<<8192, 256, 0, stream>>>(x, x_bf, Wqkv, WqkvT, Wout, WoutT);

    gemm_dbuf_k<128, true><<<dim3(24, 32), 256, 0, stream>>>(
        x_bf, WqkvT, bqkv, (void*)qk_bf, vt_bf, 4096, 3072, 1024);

    flash_attn_k<<<dim3(32, 32), 256, 0, stream>>>(qk_bf, vt_bf, attn_bf);

    gemm_dbuf_k<64, false><<<dim3(16, 32), 256, 0, stream>>>(
        attn_bf, WoutT, bout, (void*)out, nullptr, 4096, 1024, 1024);
}